// Round 1
// baseline (175.964 us; speedup 1.0000x reference)
//
#include <hip/hip_runtime.h>
#include <math.h>

#define B_FIXED 32
#define L_IN 256000
#define T_FR 1601
#define T_PAD 1616
#define NMEL_K 64
#define NH 256        // complex FFT length (512 real / 2)
#define F_BINS 257
#define HOP_K 160
#define PRE_E 0.97f
#define LOG_GUARD_K 5.9604644775390625e-08f  // 2^-24

// base-4 digit reversal of 4 digits (index < 256)
__device__ __forceinline__ int drev4(int m) {
  return ((m & 3) << 6) | (((m >> 2) & 3) << 4) | (((m >> 4) & 3) << 2) | ((m >> 6) & 3);
}

// K0: find nonzero range [lo, lo+cnt) of each mel filter row (slaney triangles are contiguous)
__global__ void fb_ranges_kernel(const float* __restrict__ fb, int* __restrict__ lo,
                                 int* __restrict__ cnt) {
  int m = threadIdx.x;  // 64 threads
  int first = F_BINS, last = -1;
  for (int f = 0; f < F_BINS; ++f) {
    float v = fb[m * F_BINS + f];
    if (v > 0.0f) { if (f < first) first = f; last = f; }
  }
  lo[m] = (last >= first) ? first : 0;
  cnt[m] = (last >= first) ? (last - first + 1) : 0;
}

// K1: one 64-thread block per frame. preemph+reflect-pad+window -> packed 256-pt
// complex radix-4 FFT (LDS) -> real-FFT unpack -> power spectrum -> sparse mel -> logmel.
__global__ void __launch_bounds__(64) frame_fft_mel_kernel(
    const float* __restrict__ x, const float* __restrict__ window,
    const float* __restrict__ fb, const int* __restrict__ lo,
    const int* __restrict__ cnt, float* __restrict__ out) {
  __shared__ float zz[2 * NH];    // interleaved complex work array
  __shared__ float pw[F_BINS];    // power spectrum
  const int tid = threadIdx.x;
  const int fid = blockIdx.x;
  const int b = fid / T_FR;
  const int t = fid - b * T_FR;
  const float* xb = x + (size_t)b * L_IN;
  const int base = t * HOP_K - 256;

  // load + preemphasis + reflect pad + window; pack pairs into digit-reversed complex slots
#pragma unroll
  for (int r = 0; r < 8; ++r) {
    int n = r * 64 + tid;
    int i = base + n;
    i = (i < 0) ? -i : i;
    i = (i >= L_IN) ? (2 * L_IN - 2 - i) : i;
    float v = (i == 0) ? xb[0] : fmaf(-PRE_E, xb[i - 1], xb[i]);
    v *= window[n];
    int m = n >> 1;
    zz[2 * drev4(m) + (n & 1)] = v;
  }
  __syncthreads();

  // 4 radix-4 DIT stages (input digit-reversed, output natural)
#pragma unroll
  for (int s = 0; s < 4; ++s) {
    const int Lq = 1 << (2 * s);
    const int grp = tid >> (2 * s);
    const int pos = tid & (Lq - 1);
    const int i0 = grp * (Lq << 2) + pos;
    const int i1 = i0 + Lq, i2 = i1 + Lq, i3 = i2 + Lq;
    float x0r = zz[2 * i0], x0i = zz[2 * i0 + 1];
    float x1r = zz[2 * i1], x1i = zz[2 * i1 + 1];
    float x2r = zz[2 * i2], x2i = zz[2 * i2 + 1];
    float x3r = zz[2 * i3], x3i = zz[2 * i3 + 1];
    float ang = -6.283185307179586f * (float)pos / (float)(Lq << 2);
    float c1, s1;
    __sincosf(ang, &s1, &c1);
    float c2 = c1 * c1 - s1 * s1, s2 = 2.f * c1 * s1;
    float c3 = c2 * c1 - s2 * s1, s3 = s2 * c1 + c2 * s1;
    float a1r = c1 * x1r - s1 * x1i, a1i = c1 * x1i + s1 * x1r;
    float a2r = c2 * x2r - s2 * x2i, a2i = c2 * x2i + s2 * x2r;
    float a3r = c3 * x3r - s3 * x3i, a3i = c3 * x3i + s3 * x3r;
    float t0r = x0r + a2r, t0i = x0i + a2i;
    float t1r = x0r - a2r, t1i = x0i - a2i;
    float t2r = a1r + a3r, t2i = a1i + a3i;
    float t3r = a1i - a3i, t3i = a3r - a1r;  // -i*(a1-a3)
    zz[2 * i0] = t0r + t2r; zz[2 * i0 + 1] = t0i + t2i;
    zz[2 * i1] = t1r + t3r; zz[2 * i1 + 1] = t1i + t3i;
    zz[2 * i2] = t0r - t2r; zz[2 * i2 + 1] = t0i - t2i;
    zz[2 * i3] = t1r - t3r; zz[2 * i3 + 1] = t1i - t3i;
    __syncthreads();
  }

  // unpack packed-real FFT -> power spectrum, k in [0,256]
#pragma unroll
  for (int q = 0; q < 4; ++q) {
    int k = q * 64 + tid;
    int kk = (NH - k) & (NH - 1);
    float zkr = zz[2 * k], zki = zz[2 * k + 1];
    float zqr = zz[2 * kk], zqi = zz[2 * kk + 1];
    float Er = 0.5f * (zkr + zqr), Ei = 0.5f * (zki - zqi);
    float Or = 0.5f * (zki + zqi), Oi = 0.5f * (zqr - zkr);
    float ang = -0.0122718463030851292f * (float)k;  // -pi/256 * k
    float c, sn;
    __sincosf(ang, &sn, &c);
    float Xr = Er + c * Or - sn * Oi;
    float Xi = Ei + c * Oi + sn * Or;
    pw[k] = Xr * Xr + Xi * Xi;
  }
  if (tid == 0) { float d = zz[0] - zz[1]; pw[NH] = d * d; }
  __syncthreads();

  // sparse mel projection: thread == mel index, gather over its contiguous bin range
  int l = lo[tid], n = cnt[tid];
  const float* fbr = fb + tid * F_BINS + l;
  float acc = 0.f;
  for (int j = 0; j < n; ++j) acc = fmaf(fbr[j], pw[l + j], acc);
  out[((size_t)b * NMEL_K + tid) * T_PAD + t] = __logf(acc + LOG_GUARD_K);
}

// K2: one 256-thread block per (b, mel) row: masked mean / unbiased var, normalize
// in place, zero padding tail, write feat_len (as float) once per b.
__global__ void __launch_bounds__(256) norm_kernel(const int* __restrict__ seq_len,
                                                   float* __restrict__ out,
                                                   float* __restrict__ fl_out) {
  const int bm = blockIdx.x;
  const int b = bm >> 6;
  const int m = bm & 63;
  const int tid = threadIdx.x;
  const int fl = seq_len[b] / HOP_K + 1;
  float* row = out + (size_t)bm * T_PAD;
  float vals[7];
  float s = 0.f;
#pragma unroll
  for (int q = 0; q < 7; ++q) {
    int t = q * 256 + tid;
    float v = (t < T_FR) ? row[t] : 0.f;
    vals[q] = v;
    if (t < fl) s += v;
  }
  __shared__ float red[4];
  __shared__ float bc[2];
#pragma unroll
  for (int off = 32; off > 0; off >>= 1) s += __shfl_down(s, off, 64);
  if ((tid & 63) == 0) red[tid >> 6] = s;
  __syncthreads();
  if (tid == 0) bc[0] = (red[0] + red[1] + red[2] + red[3]) / (float)fl;
  __syncthreads();
  const float mean = bc[0];
  float s2 = 0.f;
#pragma unroll
  for (int q = 0; q < 7; ++q) {
    int t = q * 256 + tid;
    if (t < fl) { float d = vals[q] - mean; s2 = fmaf(d, d, s2); }
  }
#pragma unroll
  for (int off = 32; off > 0; off >>= 1) s2 += __shfl_down(s2, off, 64);
  if ((tid & 63) == 0) red[tid >> 6] = s2;
  __syncthreads();
  if (tid == 0) {
    float var = (red[0] + red[1] + red[2] + red[3]) / (float)(fl - 1);
    bc[1] = 1.0f / (sqrtf(var) + 1e-5f);
  }
  __syncthreads();
  const float istd = bc[1];
#pragma unroll
  for (int q = 0; q < 7; ++q) {
    int t = q * 256 + tid;
    if (t < T_PAD) row[t] = (t < fl) ? (vals[q] - mean) * istd : 0.f;
  }
  if (m == 0 && tid == 0) fl_out[b] = (float)fl;
}

extern "C" void kernel_launch(void* const* d_in, const int* in_sizes, int n_in,
                              void* d_out, int out_size, void* d_ws, size_t ws_size,
                              hipStream_t stream) {
  const float* x = (const float*)d_in[0];
  const int* seq_len = (const int*)d_in[1];
  const float* window = (const float*)d_in[2];
  const float* fb = (const float*)d_in[3];
  const int B = in_sizes[1];  // 32
  float* out = (float*)d_out;
  float* fl_out = out + (size_t)B * NMEL_K * T_PAD;
  int* lo = (int*)d_ws;
  int* cnt = lo + 64;

  fb_ranges_kernel<<<1, 64, 0, stream>>>(fb, lo, cnt);
  frame_fft_mel_kernel<<<B * T_FR, 64, 0, stream>>>(x, window, fb, lo, cnt, out);
  norm_kernel<<<B * NMEL_K, 256, 0, stream>>>(seq_len, out, fl_out);
}

// Round 2
// 170.048 us; speedup vs baseline: 1.0348x; 1.0348x over previous
//
#include <hip/hip_runtime.h>
#include <math.h>

#define L_IN 256000
#define T_FR 1601
#define T_PAD 1616
#define NMEL_K 64
#define NH 256        // complex FFT length (512 real / 2)
#define F_BINS 257
#define HOP_K 160
#define PRE_E 0.97f
#define LOG_GUARD_K 5.9604644775390625e-08f  // 2^-24
#define FPB 16        // frames per block
#define CONC 4        // concurrent frames (one per wave)
#define GROUPS 101    // ceil(1601/16)
#define SPAN 2912     // 160*(FPB-1) + 512
#define PD(i) ((i) + ((i) >> 3))   // LDS anti-conflict padding

// base-4 digit reversal of 4 digits (index < 256)
__device__ __forceinline__ int drev4(int m) {
  return ((m & 3) << 6) | (((m >> 2) & 3) << 4) | (((m >> 4) & 3) << 2) | ((m >> 6) & 3);
}

// K0: nonzero range [lo, lo+cnt) of each mel filter row (slaney triangles contiguous)
__global__ void fb_ranges_kernel(const float* __restrict__ fb, int* __restrict__ lo,
                                 int* __restrict__ cnt) {
  int m = threadIdx.x;  // 64 threads
  int first = F_BINS, last = -1;
  for (int f = 0; f < F_BINS; ++f) {
    float v = fb[m * F_BINS + f];
    if (v > 0.0f) { if (f < first) first = f; last = f; }
  }
  lo[m] = (last >= first) ? first : 0;
  cnt[m] = (last >= first) ? (last - first + 1) : 0;
}

// K1: one 256-thread block per (b, group-of-16-frames). Shared input staging,
// per-wave 256-pt complex radix-4 FFT in padded split LDS arrays, sparse mel,
// coalesced 16-wide row-segment stores.
__global__ void __launch_bounds__(256) frame_fft_mel_kernel(
    const float* __restrict__ x, const float* __restrict__ window,
    const float* __restrict__ fb, const int* __restrict__ lo,
    const int* __restrict__ cnt, float* __restrict__ out) {
  __shared__ float xs[SPAN];            // preemphasized, reflected input span
  __shared__ float win_s[512];
  __shared__ float zr[CONC][PD(255) + 1];
  __shared__ float zi[CONC][PD(255) + 1];
  __shared__ float pw[CONC][260];
  __shared__ float outm[NMEL_K][FPB + 1];  // +1 pad: stride 17 kills store conflicts

  const int tid = threadIdx.x;
  const int w = tid >> 6;      // wave id = concurrent-frame slot
  const int lane = tid & 63;
  const int b = blockIdx.x / GROUPS;
  const int g = blockIdx.x - b * GROUPS;
  const int t0 = g * FPB;
  const float* xb = x + (size_t)b * L_IN;
  const int base = t0 * HOP_K - 256;

  // stage window
  win_s[tid] = window[tid];
  win_s[tid + 256] = window[tid + 256];
  // stage input span: preemph + reflect
  for (int n = tid; n < SPAN; n += 256) {
    int i = base + n;
    i = (i < 0) ? -i : i;
    i = (i >= L_IN) ? (2 * L_IN - 2 - i) : i;
    float v = (i == 0) ? xb[0] : fmaf(-PRE_E, xb[i - 1], xb[i]);
    xs[n] = v;
  }
  __syncthreads();

  for (int c = 0; c < FPB / CONC; ++c) {
    const int j = c * CONC + w;      // frame within group (this wave's frame)
    const int off = j * HOP_K;

    // windowed load, pack pairs, digit-reversed scatter into split arrays
#pragma unroll
    for (int r = 0; r < 4; ++r) {
      int m = r * 64 + lane;
      float v0 = xs[off + 2 * m] * win_s[2 * m];
      float v1 = xs[off + 2 * m + 1] * win_s[2 * m + 1];
      int d = PD(drev4(m));
      zr[w][d] = v0;
      zi[w][d] = v1;
    }
    __syncthreads();

    // 4 radix-4 DIT stages
#pragma unroll
    for (int s = 0; s < 4; ++s) {
      const int Lq = 1 << (2 * s);
      const int grp = lane >> (2 * s);
      const int pos = lane & (Lq - 1);
      const int i0 = grp * (Lq << 2) + pos;
      const int i1 = i0 + Lq, i2 = i1 + Lq, i3 = i2 + Lq;
      float x0r = zr[w][PD(i0)], x0i = zi[w][PD(i0)];
      float x1r = zr[w][PD(i1)], x1i = zi[w][PD(i1)];
      float x2r = zr[w][PD(i2)], x2i = zi[w][PD(i2)];
      float x3r = zr[w][PD(i3)], x3i = zi[w][PD(i3)];
      float ang = -6.283185307179586f * (float)pos / (float)(Lq << 2);
      float c1, s1;
      __sincosf(ang, &s1, &c1);
      float c2 = c1 * c1 - s1 * s1, s2 = 2.f * c1 * s1;
      float c3 = c2 * c1 - s2 * s1, s3 = s2 * c1 + c2 * s1;
      float a1r = c1 * x1r - s1 * x1i, a1i = c1 * x1i + s1 * x1r;
      float a2r = c2 * x2r - s2 * x2i, a2i = c2 * x2i + s2 * x2r;
      float a3r = c3 * x3r - s3 * x3i, a3i = c3 * x3i + s3 * x3r;
      float t0r = x0r + a2r, t0i = x0i + a2i;
      float t1r = x0r - a2r, t1i = x0i - a2i;
      float t2r = a1r + a3r, t2i = a1i + a3i;
      float t3r = a1i - a3i, t3i = a3r - a1r;  // -i*(a1-a3)
      zr[w][PD(i0)] = t0r + t2r; zi[w][PD(i0)] = t0i + t2i;
      zr[w][PD(i1)] = t1r + t3r; zi[w][PD(i1)] = t1i + t3i;
      zr[w][PD(i2)] = t0r - t2r; zi[w][PD(i2)] = t0i - t2i;
      zr[w][PD(i3)] = t1r - t3r; zi[w][PD(i3)] = t1i - t3i;
      __syncthreads();
    }

    // packed-real unpack -> power spectrum
#pragma unroll
    for (int q = 0; q < 4; ++q) {
      int k = q * 64 + lane;
      int kk = (NH - k) & (NH - 1);
      float zkr = zr[w][PD(k)], zki = zi[w][PD(k)];
      float zqr = zr[w][PD(kk)], zqi = zi[w][PD(kk)];
      float Er = 0.5f * (zkr + zqr), Ei = 0.5f * (zki - zqi);
      float Or = 0.5f * (zki + zqi), Oi = 0.5f * (zqr - zkr);
      float ang = -0.0122718463030851292f * (float)k;  // -pi/256 * k
      float cq, sq;
      __sincosf(ang, &sq, &cq);
      float Xr = Er + cq * Or - sq * Oi;
      float Xi = Ei + cq * Oi + sq * Or;
      pw[w][k] = Xr * Xr + Xi * Xi;
    }
    if (lane == 0) { float d = zr[w][PD(0)] - zi[w][PD(0)]; pw[w][NH] = d * d; }
    __syncthreads();

    // sparse mel projection: lane == mel index
    {
      int l = lo[lane], n = cnt[lane];
      const float* fbr = fb + lane * F_BINS + l;
      float acc = 0.f;
      for (int jb = 0; jb < n; ++jb) acc = fmaf(fbr[jb], pw[w][l + jb], acc);
      outm[lane][j] = __logf(acc + LOG_GUARD_K);
    }
    __syncthreads();
  }

  // coalesced store: 16 consecutive t per mel row = one 64B segment
#pragma unroll
  for (int p = 0; p < 4; ++p) {
    int row = p * 16 + (tid >> 4);
    int jj = tid & 15;
    int t = t0 + jj;
    if (t < T_FR)
      out[((size_t)b * NMEL_K + row) * T_PAD + t] = outm[row][jj];
  }
}

// K2: one 256-thread block per (b, mel) row: masked mean / unbiased var, normalize
// in place, zero padding tail, write feat_len (as float) once per b.
__global__ void __launch_bounds__(256) norm_kernel(const int* __restrict__ seq_len,
                                                   float* __restrict__ out,
                                                   float* __restrict__ fl_out) {
  const int bm = blockIdx.x;
  const int b = bm >> 6;
  const int m = bm & 63;
  const int tid = threadIdx.x;
  const int fl = seq_len[b] / HOP_K + 1;
  float* row = out + (size_t)bm * T_PAD;
  float vals[7];
  float s = 0.f;
#pragma unroll
  for (int q = 0; q < 7; ++q) {
    int t = q * 256 + tid;
    float v = (t < T_FR) ? row[t] : 0.f;
    vals[q] = v;
    if (t < fl) s += v;
  }
  __shared__ float red[4];
  __shared__ float bc[2];
#pragma unroll
  for (int off = 32; off > 0; off >>= 1) s += __shfl_down(s, off, 64);
  if ((tid & 63) == 0) red[tid >> 6] = s;
  __syncthreads();
  if (tid == 0) bc[0] = (red[0] + red[1] + red[2] + red[3]) / (float)fl;
  __syncthreads();
  const float mean = bc[0];
  float s2 = 0.f;
#pragma unroll
  for (int q = 0; q < 7; ++q) {
    int t = q * 256 + tid;
    if (t < fl) { float d = vals[q] - mean; s2 = fmaf(d, d, s2); }
  }
#pragma unroll
  for (int off = 32; off > 0; off >>= 1) s2 += __shfl_down(s2, off, 64);
  if ((tid & 63) == 0) red[tid >> 6] = s2;
  __syncthreads();
  if (tid == 0) {
    float var = (red[0] + red[1] + red[2] + red[3]) / (float)(fl - 1);
    bc[1] = 1.0f / (sqrtf(var) + 1e-5f);
  }
  __syncthreads();
  const float istd = bc[1];
#pragma unroll
  for (int q = 0; q < 7; ++q) {
    int t = q * 256 + tid;
    if (t < T_PAD) row[t] = (t < fl) ? (vals[q] - mean) * istd : 0.f;
  }
  if (m == 0 && tid == 0) fl_out[b] = (float)fl;
}

extern "C" void kernel_launch(void* const* d_in, const int* in_sizes, int n_in,
                              void* d_out, int out_size, void* d_ws, size_t ws_size,
                              hipStream_t stream) {
  const float* x = (const float*)d_in[0];
  const int* seq_len = (const int*)d_in[1];
  const float* window = (const float*)d_in[2];
  const float* fb = (const float*)d_in[3];
  const int B = in_sizes[1];  // 32
  float* out = (float*)d_out;
  float* fl_out = out + (size_t)B * NMEL_K * T_PAD;
  int* lo = (int*)d_ws;
  int* cnt = lo + 64;

  fb_ranges_kernel<<<1, 64, 0, stream>>>(fb, lo, cnt);
  frame_fft_mel_kernel<<<B * GROUPS, 256, 0, stream>>>(x, window, fb, lo, cnt, out);
  norm_kernel<<<B * NMEL_K, 256, 0, stream>>>(seq_len, out, fl_out);
}

// Round 3
// 137.195 us; speedup vs baseline: 1.2826x; 1.2395x over previous
//
#include <hip/hip_runtime.h>
#include <math.h>

#define L_IN 256000
#define T_FR 1601
#define T_PAD 1616
#define NMEL_K 64
#define F_BINS 257
#define HOP_K 160
#define PRE_E 0.97f
#define LOG_GUARD_K 5.9604644775390625e-08f  // 2^-24
#define FPB 16        // frames per block
#define CONC 4        // one frame per wave
#define GROUPS 101    // ceil(1601/16)
#define SPAN 2912     // 160*(FPB-1) + 512

__device__ __forceinline__ float2 cmulf(float2 a, float2 b) {
  return make_float2(a.x * b.x - a.y * b.y, a.x * b.y + a.y * b.x);
}

// Prep: per-mel compact filterbank (32 wide, 16B-aligned start, zero-padded) + aligned lo.
// 64 blocks x 64 threads; parallel scan replaces the old serial 1-block kernel.
__global__ void prep_kernel(const float* __restrict__ fb, float* __restrict__ fbc,
                            int* __restrict__ loAlG) {
  const int m = blockIdx.x;
  const int t = threadIdx.x;
  int first = 512, last = -1;
  for (int c = 0; c < 5; ++c) {
    int f = t + 64 * c;
    if (f < F_BINS) {
      float v = fb[m * F_BINS + f];
      if (v > 0.0f) { first = min(first, f); last = max(last, f); }
    }
  }
  for (int off = 32; off > 0; off >>= 1) {
    first = min(first, __shfl_xor(first, off));
    last = max(last, __shfl_xor(last, off));
  }
  int lo = (first <= last) ? first : 0;
  int lastv = (first <= last) ? last : 0;
  int la = lo & ~3;
  if (t == 0) loAlG[m] = la;
  if (t < 32) {
    int f = la + t;
    float v = (f >= lo && f <= lastv && f < F_BINS) ? fb[m * F_BINS + f] : 0.0f;
    fbc[m * 32 + t] = v;
  }
}

// K1: 256 threads = 4 waves, 16 frames per block. Register 4-step FFT:
// FFT_4 over q in regs -> twiddle -> FFT_64 across lanes via 6 shfl_xor radix-2
// stages (DIF, bit-reversed out) -> packed-real unpack in regs -> pw quad to LDS
// -> uniform 8x float4 mel gather. No intra-frame barriers, no hot-loop sincos.
__global__ void __launch_bounds__(256) frame_fft_mel_kernel(
    const float* __restrict__ x, const float* __restrict__ window,
    const float* __restrict__ fbc, const int* __restrict__ loAlG,
    float* __restrict__ out) {
  __shared__ __align__(16) float xs[SPAN];
  __shared__ __align__(16) float pw[CONC][288];
  __shared__ float outm[NMEL_K][FPB + 1];

  const int tid = threadIdx.x;
  const int w = tid >> 6;
  const int lane = tid & 63;
  const int b = blockIdx.x / GROUPS;
  const int g = blockIdx.x - b * GROUPS;
  const int t0 = g * FPB;
  const float* xb = x + (size_t)b * L_IN;
  const int base = t0 * HOP_K - 256;

  // stage input span: preemph + reflect
  for (int n = tid; n < SPAN; n += 256) {
    int i = base + n;
    i = (i < 0) ? -i : i;
    i = (i >= L_IN) ? (2 * L_IN - 2 - i) : i;
    xs[n] = (i == 0) ? xb[0] : fmaf(-PRE_E, xb[i - 1], xb[i]);
  }

  // ---- per-lane frame-invariant constants (all hoisted) ----
  const int sig = __builtin_bitreverse32(lane) >> 26;  // bitrev6(lane)
  float wr[4], wi[4];
#pragma unroll
  for (int q = 0; q < 4; ++q) {
    float2 wv = *(const float2*)(window + 2 * (lane + 64 * q));
    wr[q] = wv.x; wi[q] = wv.y;
  }
  float2 tw1, tw2, tw3;  // W256^(l*r)
  {
    float a = -0.024543692606170259f * (float)lane;  // -2*pi/256
    __sincosf(a, &tw1.y, &tw1.x);
    tw2 = cmulf(tw1, tw1);
    tw3 = cmulf(tw2, tw1);
  }
  float stc[6], sts[6];  // DIF stage twiddles W_{2H}^{lane&(H-1)}
#pragma unroll
  for (int i = 0; i < 6; ++i) {
    int H = 32 >> i;
    int p = lane & (H - 1);
    float a = -3.14159265358979323846f * (float)p / (float)H;
    __sincosf(a, &sts[i], &stc[i]);
  }
  float cu[4], su[4];  // unpack twiddle e^{-i*pi*(4*sig+r)/256}
  {
    float a = -0.049087385212340519f * (float)sig;  // -pi/64
    float cb, sb;
    __sincosf(a, &sb, &cb);
    const float C[4] = {1.0f, 0.99992470183914454f, 0.99969881869620425f, 0.99932238458834954f};
    const float S[4] = {0.0f, 0.01227153828571993f, 0.02454122852291229f, 0.03680722294135883f};
#pragma unroll
    for (int r = 0; r < 4; ++r) {
      cu[r] = cb * C[r] + sb * S[r];
      su[r] = sb * C[r] - cb * S[r];
    }
  }
  const int idx0 = __builtin_bitreverse32((64 - sig) & 63) >> 26;  // lane of Y0[(64-s)&63]
  const int la = loAlG[lane];
  const float4* fr4 = (const float4*)fbc + lane * 8;

  __syncthreads();

  for (int c = 0; c < FPB / CONC; ++c) {
    const int j = c * CONC + w;
    const int off = j * HOP_K;

    float Br[4], Bi[4];
    {
      float zr[4], zi[4];
#pragma unroll
      for (int q = 0; q < 4; ++q) {
        float2 v = *(const float2*)(xs + off + 2 * (lane + 64 * q));
        zr[q] = v.x * wr[q];
        zi[q] = v.y * wi[q];
      }
      // FFT_4 over q (W4 = -i), then W256^{l*r} twiddle
      float e0r = zr[0] + zr[2], e0i = zi[0] + zi[2];
      float e1r = zr[1] + zr[3], e1i = zi[1] + zi[3];
      float d0r = zr[0] - zr[2], d0i = zi[0] - zi[2];
      float d1r = zr[1] - zr[3], d1i = zi[1] - zi[3];
      Br[0] = e0r + e1r; Bi[0] = e0i + e1i;
      float A2r = e0r - e1r, A2i = e0i - e1i;
      float A1r = d0r + d1i, A1i = d0i - d1r;
      float A3r = d0r - d1i, A3i = d0i + d1r;
      Br[1] = A1r * tw1.x - A1i * tw1.y; Bi[1] = A1r * tw1.y + A1i * tw1.x;
      Br[2] = A2r * tw2.x - A2i * tw2.y; Bi[2] = A2r * tw2.y + A2i * tw2.x;
      Br[3] = A3r * tw3.x - A3i * tw3.y; Bi[3] = A3r * tw3.y + A3i * tw3.x;
    }

    // FFT_64 across lanes: 6 DIF radix-2 stages, H = 32..1
#pragma unroll
    for (int i = 0; i < 6; ++i) {
      const int H = 32 >> i;
      const bool hi = (lane & H) != 0;
      const float cc = stc[i], ss = sts[i];
#pragma unroll
      for (int r = 0; r < 4; ++r) {
        float tr = __shfl_xor(Br[r], H);
        float ti = __shfl_xor(Bi[r], H);
        float sr = Br[r] + tr, si = Bi[r] + ti;
        float dr = tr - Br[r], di = ti - Bi[r];
        float pr = dr * cc - di * ss, pi = dr * ss + di * cc;
        Br[r] = hi ? pr : sr;
        Bi[r] = hi ? pi : si;
      }
    }
    // lane now holds Z[4*sig + r] = Y_r[sig]

    // packed-real unpack + power spectrum (k = 4*sig + r)
    {
      float q3r = __shfl_xor(Br[3], 63), q3i = __shfl_xor(Bi[3], 63);
      float q2r = __shfl_xor(Br[2], 63), q2i = __shfl_xor(Bi[2], 63);
      float q1r = __shfl_xor(Br[1], 63), q1i = __shfl_xor(Bi[1], 63);
      float q0r = __shfl(Br[0], idx0), q0i = __shfl(Bi[0], idx0);
      float qr[4] = {q0r, q3r, q2r, q1r};
      float qi_[4] = {q0i, q3i, q2i, q1i};
      float pv[4];
#pragma unroll
      for (int r = 0; r < 4; ++r) {
        float Er = 0.5f * (Br[r] + qr[r]);
        float Ei = 0.5f * (Bi[r] - qi_[r]);
        float Or = 0.5f * (Bi[r] + qi_[r]);
        float Oi = 0.5f * (qr[r] - Br[r]);
        float Xr = Er + cu[r] * Or - su[r] * Oi;
        float Xi = Ei + cu[r] * Oi + su[r] * Or;
        pv[r] = Xr * Xr + Xi * Xi;
      }
      ((float4*)pw[w])[sig] = make_float4(pv[0], pv[1], pv[2], pv[3]);
      if (lane == 0) { float d = Br[0] - Bi[0]; pw[w][256] = d * d; }
      else if (lane < 32) pw[w][256 + lane] = 0.0f;  // zero tail for gather overrun
    }
    __builtin_amdgcn_wave_barrier();

    // uniform mel gather: 8 x (global fbc quad, LDS pw quad)
    {
      const float4* pq = (const float4*)pw[w] + (la >> 2);
      float acc = 0.0f;
#pragma unroll
      for (int jj = 0; jj < 8; ++jj) {
        float4 wq = fr4[jj];
        float4 p = pq[jj];
        acc = fmaf(wq.x, p.x, acc);
        acc = fmaf(wq.y, p.y, acc);
        acc = fmaf(wq.z, p.z, acc);
        acc = fmaf(wq.w, p.w, acc);
      }
      outm[lane][j] = __logf(acc + LOG_GUARD_K);
    }
    __builtin_amdgcn_wave_barrier();
  }

  __syncthreads();
  // coalesced store: 16 consecutive t per mel row
#pragma unroll
  for (int p = 0; p < 4; ++p) {
    int row = p * 16 + (tid >> 4);
    int jj = tid & 15;
    int t = t0 + jj;
    if (t < T_FR)
      out[((size_t)b * NMEL_K + row) * T_PAD + t] = outm[row][jj];
  }
}

// K2: one 256-thread block per (b, mel) row: masked mean / unbiased var, normalize,
// zero tail, write feat_len (as float) once per b.
__global__ void __launch_bounds__(256) norm_kernel(const int* __restrict__ seq_len,
                                                   float* __restrict__ out,
                                                   float* __restrict__ fl_out) {
  const int bm = blockIdx.x;
  const int b = bm >> 6;
  const int m = bm & 63;
  const int tid = threadIdx.x;
  const int fl = seq_len[b] / HOP_K + 1;
  float* row = out + (size_t)bm * T_PAD;
  float vals[7];
  float s = 0.f;
#pragma unroll
  for (int q = 0; q < 7; ++q) {
    int t = q * 256 + tid;
    float v = (t < T_FR) ? row[t] : 0.f;
    vals[q] = v;
    if (t < fl) s += v;
  }
  __shared__ float red[4];
  __shared__ float bc[2];
#pragma unroll
  for (int off = 32; off > 0; off >>= 1) s += __shfl_down(s, off, 64);
  if ((tid & 63) == 0) red[tid >> 6] = s;
  __syncthreads();
  if (tid == 0) bc[0] = (red[0] + red[1] + red[2] + red[3]) / (float)fl;
  __syncthreads();
  const float mean = bc[0];
  float s2 = 0.f;
#pragma unroll
  for (int q = 0; q < 7; ++q) {
    int t = q * 256 + tid;
    if (t < fl) { float d = vals[q] - mean; s2 = fmaf(d, d, s2); }
  }
#pragma unroll
  for (int off = 32; off > 0; off >>= 1) s2 += __shfl_down(s2, off, 64);
  if ((tid & 63) == 0) red[tid >> 6] = s2;
  __syncthreads();
  if (tid == 0) {
    float var = (red[0] + red[1] + red[2] + red[3]) / (float)(fl - 1);
    bc[1] = 1.0f / (sqrtf(var) + 1e-5f);
  }
  __syncthreads();
  const float istd = bc[1];
#pragma unroll
  for (int q = 0; q < 7; ++q) {
    int t = q * 256 + tid;
    if (t < T_PAD) row[t] = (t < fl) ? (vals[q] - mean) * istd : 0.f;
  }
  if (m == 0 && tid == 0) fl_out[b] = (float)fl;
}

extern "C" void kernel_launch(void* const* d_in, const int* in_sizes, int n_in,
                              void* d_out, int out_size, void* d_ws, size_t ws_size,
                              hipStream_t stream) {
  const float* x = (const float*)d_in[0];
  const int* seq_len = (const int*)d_in[1];
  const float* window = (const float*)d_in[2];
  const float* fb = (const float*)d_in[3];
  const int B = in_sizes[1];  // 32
  float* out = (float*)d_out;
  float* fl_out = out + (size_t)B * NMEL_K * T_PAD;
  float* fbc = (float*)d_ws;                 // 64*32 floats
  int* loAlG = (int*)d_ws + 2048;

  prep_kernel<<<NMEL_K, 64, 0, stream>>>(fb, fbc, loAlG);
  frame_fft_mel_kernel<<<B * GROUPS, 256, 0, stream>>>(x, window, fbc, loAlG, out);
  norm_kernel<<<B * NMEL_K, 256, 0, stream>>>(seq_len, out, fl_out);
}